// Round 1
// baseline (476.048 us; speedup 1.0000x reference)
//
#include <hip/hip_runtime.h>
#include <hip/hip_bf16.h>
#include <stdint.h>

// Per-edge gathered 8x8 matvec, bf16 weights (converted into d_ws each call).
// Round-4 change: (a) two-pass weight slicing -- pass 0 blocks handle
// widx < NUM_W/2, pass 1 the rest, so the live weight slice (4.2 MB bf16)
// fits one XCD's 4 MB L2; (b) non-temporal loads/stores on all zero-reuse
// streams (idx, x, out) so the 134 MB output write-allocate and the 32 MB
// value gather stop evicting the weight slice. W loads stay cached.
// Theory: wall is L2 miss traffic on the gathers (fetch 485 MB vs 200 B/edge
// compulsory); target is W-miss elimination, predict fetch -> ~350 MB.

typedef float          f32x4 __attribute__((ext_vector_type(4)));
typedef unsigned int   u32x4 __attribute__((ext_vector_type(4)));
typedef unsigned short u16x4 __attribute__((ext_vector_type(4)));

__device__ __forceinline__ float bflo(uint32_t u) {
    union { uint32_t u; float f; } c; c.u = u << 16; return c.f;
}
__device__ __forceinline__ float bfhi(uint32_t u) {
    union { uint32_t u; float f; } c; c.u = u & 0xffff0000u; return c.f;
}

// ---- weight table fp32 -> bf16 (RNE via __float2bfloat16) ----
__global__ __launch_bounds__(256) void convert_weights_kernel(
    const f32x4* __restrict__ src,
    u16x4*       __restrict__ dst,
    int n4)
{
    int i = blockIdx.x * blockDim.x + threadIdx.x;
    if (i >= n4) return;
    f32x4 v = __builtin_nontemporal_load(&src[i]);
    u16x4 r;
    r.x = __bfloat16_as_ushort(__float2bfloat16(v.x));
    r.y = __bfloat16_as_ushort(__float2bfloat16(v.y));
    r.z = __bfloat16_as_ushort(__float2bfloat16(v.z));
    r.w = __bfloat16_as_ushort(__float2bfloat16(v.w));
    __builtin_nontemporal_store(r, &dst[i]);
}

// ---- main: thread-per-output, bf16 weights, 2-pass weight slicing ----
__global__ __launch_bounds__(256) void edge_linear_bf16w_2pass_kernel(
    const float*    __restrict__ values,     // fp32[NUM_VALUES][8]
    const uint32_t* __restrict__ wbf,        // bf16[NUM_W][8][8] as uint32[.][32]
    const int*      __restrict__ input_idx,  // [E]
    const int*      __restrict__ weight_idx, // [E]
    float*          __restrict__ out,        // fp32[E][8]
    int E, int blocksPerPass, int wThresh)
{
    int pass = (blockIdx.x >= (unsigned)blocksPerPass) ? 1 : 0;
    int bx   = blockIdx.x - pass * blocksPerPass;
    int gid  = bx * blockDim.x + threadIdx.x;
    int e = gid >> 3;
    if (e >= E) return;
    int o = gid & 7;

    int widx = __builtin_nontemporal_load(&weight_idx[e]);
    int p = (widx >= wThresh) ? 1 : 0;
    if (p != pass) return;                 // other pass owns this edge

    int iidx = __builtin_nontemporal_load(&input_idx[e]);

    const f32x4* xp = (const f32x4*)(values + (size_t)iidx * 8u);
    const u32x4* wp = (const u32x4*)(wbf + (size_t)widx * 32u + (uint32_t)o * 4u);

    u32x4 wv = *wp;                                   // cached: L2-resident slice
    f32x4 x0 = __builtin_nontemporal_load(xp);        // zero-reuse streams: nt
    f32x4 x1 = __builtin_nontemporal_load(xp + 1);

    float acc = 0.0f;
    acc = fmaf(bflo(wv.x), x0.x, acc);
    acc = fmaf(bfhi(wv.x), x0.y, acc);
    acc = fmaf(bflo(wv.y), x0.z, acc);
    acc = fmaf(bfhi(wv.y), x0.w, acc);
    acc = fmaf(bflo(wv.z), x1.x, acc);
    acc = fmaf(bfhi(wv.z), x1.y, acc);
    acc = fmaf(bflo(wv.w), x1.z, acc);
    acc = fmaf(bfhi(wv.w), x1.w, acc);

    __builtin_nontemporal_store(acc, &out[gid]);      // no write-allocate pollution
}

// ---- fallback (round-2 kernel) if ws too small ----
__global__ __launch_bounds__(256) void edge_linear_f32_kernel(
    const float* __restrict__ values,
    const float* __restrict__ weights,
    const int*   __restrict__ input_idx,
    const int*   __restrict__ weight_idx,
    float*       __restrict__ out,
    int E)
{
    int gid = blockIdx.x * blockDim.x + threadIdx.x;
    int e = gid >> 3;
    if (e >= E) return;
    int o = gid & 7;
    int iidx = input_idx[e];
    int widx = weight_idx[e];
    const float4* xp = (const float4*)(values  + (size_t)iidx * 8u);
    const float4* wp = (const float4*)(weights + (size_t)widx * 64u + (uint32_t)o * 8u);
    float4 x0 = xp[0], x1 = xp[1], w0 = wp[0], w1 = wp[1];
    float acc = 0.0f;
    acc = fmaf(w0.x, x0.x, acc); acc = fmaf(w0.y, x0.y, acc);
    acc = fmaf(w0.z, x0.z, acc); acc = fmaf(w0.w, x0.w, acc);
    acc = fmaf(w1.x, x1.x, acc); acc = fmaf(w1.y, x1.y, acc);
    acc = fmaf(w1.z, x1.z, acc); acc = fmaf(w1.w, x1.w, acc);
    out[gid] = acc;
}

extern "C" void kernel_launch(void* const* d_in, const int* in_sizes, int n_in,
                              void* d_out, int out_size, void* d_ws, size_t ws_size,
                              hipStream_t stream) {
    const float* values     = (const float*)d_in[0];
    const float* weights    = (const float*)d_in[1];
    const int*   input_idx  = (const int*)d_in[2];
    const int*   weight_idx = (const int*)d_in[3];
    float*       out        = (float*)d_out;

    int E  = in_sizes[2];               // 4194304 edges
    int NW = in_sizes[1];               // 4194304 floats in weight table
    size_t need = (size_t)NW * sizeof(uint16_t);   // 8.4 MB bf16 table

    long long threads = (long long)E * 8;
    int block = 256;
    int blocksPerPass = (int)((threads + block - 1) / block);

    if (ws_size >= need) {
        // 1) convert weight table to bf16 in d_ws (every call; ws is re-poisoned)
        int n4 = NW / 4;
        int cgrid = (n4 + 255) / 256;
        convert_weights_kernel<<<cgrid, 256, 0, stream>>>(
            (const f32x4*)weights, (u16x4*)d_ws, n4);
        // 2) main kernel, two temporal passes over the edge list split by widx
        int numW   = NW / 64;           // 64 floats per 8x8 matrix
        int wThresh = numW >> 1;        // slice 0: [0, numW/2), slice 1: rest
        edge_linear_bf16w_2pass_kernel<<<blocksPerPass * 2, block, 0, stream>>>(
            values, (const uint32_t*)d_ws, input_idx, weight_idx, out,
            E, blocksPerPass, wThresh);
    } else {
        edge_linear_f32_kernel<<<blocksPerPass, block, 0, stream>>>(
            values, weights, input_idx, weight_idx, out, E);
    }
}

// Round 2
// 319.804 us; speedup vs baseline: 1.4886x; 1.4886x over previous
//
#include <hip/hip_runtime.h>
#include <hip/hip_bf16.h>
#include <stdint.h>

// Per-edge gathered 8x8 matvec. Round-5: revert round-4's 2-pass + nt
// experiment (fetch dropped as predicted but time 2x worse -> wall is
// line-request concurrency x latency, not HBM bytes). Single change vs
// round-0: values ALSO converted to bf16 in d_ws. x gather becomes one
// 16 B load (was 2), values footprint 33.5->16.8 MB. W stays bf16.
// absmax budget 0.48; bf16 W alone measured 0.125, predict ~0.25 now.

typedef float          f32x4 __attribute__((ext_vector_type(4)));
typedef unsigned int   u32x4 __attribute__((ext_vector_type(4)));
typedef unsigned short u16x4 __attribute__((ext_vector_type(4)));

__device__ __forceinline__ float bflo(uint32_t u) {
    union { uint32_t u; float f; } c; c.u = u << 16; return c.f;
}
__device__ __forceinline__ float bfhi(uint32_t u) {
    union { uint32_t u; float f; } c; c.u = u & 0xffff0000u; return c.f;
}

// ---- fp32 -> bf16 table convert (RNE via __float2bfloat16) ----
__global__ __launch_bounds__(256) void convert_f32_bf16_kernel(
    const f32x4* __restrict__ src,
    u16x4*       __restrict__ dst,
    int n4)
{
    int i = blockIdx.x * blockDim.x + threadIdx.x;
    if (i >= n4) return;
    f32x4 v = src[i];
    u16x4 r;
    r.x = __bfloat16_as_ushort(__float2bfloat16(v.x));
    r.y = __bfloat16_as_ushort(__float2bfloat16(v.y));
    r.z = __bfloat16_as_ushort(__float2bfloat16(v.z));
    r.w = __bfloat16_as_ushort(__float2bfloat16(v.w));
    dst[i] = r;
}

// ---- main: thread-per-output, bf16 weights AND bf16 values ----
__global__ __launch_bounds__(256) void edge_linear_bf16wv_kernel(
    const uint32_t* __restrict__ vbf,        // bf16[NUM_VALUES][8] as uint32[.][4]
    const uint32_t* __restrict__ wbf,        // bf16[NUM_W][8][8]  as uint32[.][32]
    const int*      __restrict__ input_idx,  // [E]
    const int*      __restrict__ weight_idx, // [E]
    float*          __restrict__ out,        // fp32[E][8]
    int E)
{
    int gid = blockIdx.x * blockDim.x + threadIdx.x;
    int e = gid >> 3;
    if (e >= E) return;
    int o = gid & 7;

    int iidx = input_idx[e];
    int widx = weight_idx[e];

    const u32x4* xp = (const u32x4*)(vbf + (size_t)iidx * 4u);
    const u32x4* wp = (const u32x4*)(wbf + (size_t)widx * 32u + (uint32_t)o * 4u);

    u32x4 wv = *wp;        // 8 bf16 of W row o (one 16 B load)
    u32x4 xv = *xp;        // 8 bf16 of x     (one 16 B load, was two)

    float acc = 0.0f;
    acc = fmaf(bflo(wv.x), bflo(xv.x), acc);
    acc = fmaf(bfhi(wv.x), bfhi(xv.x), acc);
    acc = fmaf(bflo(wv.y), bflo(xv.y), acc);
    acc = fmaf(bfhi(wv.y), bfhi(xv.y), acc);
    acc = fmaf(bflo(wv.z), bflo(xv.z), acc);
    acc = fmaf(bfhi(wv.z), bfhi(xv.z), acc);
    acc = fmaf(bflo(wv.w), bflo(xv.w), acc);
    acc = fmaf(bfhi(wv.w), bfhi(xv.w), acc);

    out[gid] = acc;
}

// ---- round-0 path: bf16 weights only (if ws fits just the W table) ----
__global__ __launch_bounds__(256) void edge_linear_bf16w_kernel(
    const float*    __restrict__ values,
    const uint32_t* __restrict__ wbf,
    const int*      __restrict__ input_idx,
    const int*      __restrict__ weight_idx,
    float*          __restrict__ out,
    int E)
{
    int gid = blockIdx.x * blockDim.x + threadIdx.x;
    int e = gid >> 3;
    if (e >= E) return;
    int o = gid & 7;
    int iidx = input_idx[e];
    int widx = weight_idx[e];
    const f32x4* xp = (const f32x4*)(values + (size_t)iidx * 8u);
    const u32x4* wp = (const u32x4*)(wbf + (size_t)widx * 32u + (uint32_t)o * 4u);
    u32x4 wv = *wp;
    f32x4 x0 = xp[0];
    f32x4 x1 = xp[1];
    float acc = 0.0f;
    acc = fmaf(bflo(wv.x), x0.x, acc);
    acc = fmaf(bfhi(wv.x), x0.y, acc);
    acc = fmaf(bflo(wv.y), x0.z, acc);
    acc = fmaf(bfhi(wv.y), x0.w, acc);
    acc = fmaf(bflo(wv.z), x1.x, acc);
    acc = fmaf(bfhi(wv.z), x1.y, acc);
    acc = fmaf(bflo(wv.w), x1.z, acc);
    acc = fmaf(bfhi(wv.w), x1.w, acc);
    out[gid] = acc;
}

// ---- f32 fallback ----
__global__ __launch_bounds__(256) void edge_linear_f32_kernel(
    const float* __restrict__ values,
    const float* __restrict__ weights,
    const int*   __restrict__ input_idx,
    const int*   __restrict__ weight_idx,
    float*       __restrict__ out,
    int E)
{
    int gid = blockIdx.x * blockDim.x + threadIdx.x;
    int e = gid >> 3;
    if (e >= E) return;
    int o = gid & 7;
    int iidx = input_idx[e];
    int widx = weight_idx[e];
    const float4* xp = (const float4*)(values  + (size_t)iidx * 8u);
    const float4* wp = (const float4*)(weights + (size_t)widx * 64u + (uint32_t)o * 8u);
    float4 x0 = xp[0], x1 = xp[1], w0 = wp[0], w1 = wp[1];
    float acc = 0.0f;
    acc = fmaf(w0.x, x0.x, acc); acc = fmaf(w0.y, x0.y, acc);
    acc = fmaf(w0.z, x0.z, acc); acc = fmaf(w0.w, x0.w, acc);
    acc = fmaf(w1.x, x1.x, acc); acc = fmaf(w1.y, x1.y, acc);
    acc = fmaf(w1.z, x1.z, acc); acc = fmaf(w1.w, x1.w, acc);
    out[gid] = acc;
}

extern "C" void kernel_launch(void* const* d_in, const int* in_sizes, int n_in,
                              void* d_out, int out_size, void* d_ws, size_t ws_size,
                              hipStream_t stream) {
    const float* values     = (const float*)d_in[0];
    const float* weights    = (const float*)d_in[1];
    const int*   input_idx  = (const int*)d_in[2];
    const int*   weight_idx = (const int*)d_in[3];
    float*       out        = (float*)d_out;

    int NV = in_sizes[0];               // floats in value table (8.4M)
    int NW = in_sizes[1];               // floats in weight table (4.19M)
    int E  = in_sizes[2];               // 4194304 edges

    size_t need_w  = (size_t)NW * sizeof(uint16_t);          // 8.4 MB
    size_t v_off   = (need_w + 255u) & ~(size_t)255u;        // align values table
    size_t need_wv = v_off + (size_t)NV * sizeof(uint16_t);  // + 16.8 MB

    long long threads = (long long)E * 8;
    int block = 256;
    int grid = (int)((threads + block - 1) / block);

    if (ws_size >= need_wv) {
        // convert both tables each call (ws is re-poisoned between calls)
        uint16_t* wbf = (uint16_t*)d_ws;
        uint16_t* vbf = (uint16_t*)((char*)d_ws + v_off);
        int wn4 = NW / 4;
        convert_f32_bf16_kernel<<<(wn4 + 255) / 256, 256, 0, stream>>>(
            (const f32x4*)weights, (u16x4*)wbf, wn4);
        int vn4 = NV / 4;
        convert_f32_bf16_kernel<<<(vn4 + 255) / 256, 256, 0, stream>>>(
            (const f32x4*)values, (u16x4*)vbf, vn4);
        edge_linear_bf16wv_kernel<<<grid, block, 0, stream>>>(
            (const uint32_t*)vbf, (const uint32_t*)wbf,
            input_idx, weight_idx, out, E);
    } else if (ws_size >= need_w) {
        int wn4 = NW / 4;
        convert_f32_bf16_kernel<<<(wn4 + 255) / 256, 256, 0, stream>>>(
            (const f32x4*)weights, (u16x4*)d_ws, wn4);
        edge_linear_bf16w_kernel<<<grid, block, 0, stream>>>(
            values, (const uint32_t*)d_ws, input_idx, weight_idx, out, E);
    } else {
        edge_linear_f32_kernel<<<grid, block, 0, stream>>>(
            values, weights, input_idx, weight_idx, out, E);
    }
}

// Round 3
// 319.614 us; speedup vs baseline: 1.4894x; 1.0006x over previous
//
#include <hip/hip_runtime.h>
#include <hip/hip_bf16.h>
#include <stdint.h>

// Per-edge gathered 8x8 matvec, bf16 W and V tables built in d_ws each call.
// Round-6: (a) non-temporal store on out ONLY -- the 134 MB zero-reuse output
// stream was write-allocating through the 4 MB/XCD L2s, evicting the gather
// tables (W 64x reuse, V 4x). All loads stay cached (round-4 proved nt on
// reused loads converts L3 hits into HBM misses -> 2x slower). (b) both
// fp32->bf16 table converts fused into ONE kernel launch (saves ~5 us node
// overhead; both are BW-bound streams).
// Model: time/edge = miss-lines/edge x L3-latency / TCP-miss-cap. Target is
// miss-lines/edge via L2 hit rate, not HBM bytes (never BW-bound here).

typedef float          f32x4 __attribute__((ext_vector_type(4)));
typedef unsigned int   u32x4 __attribute__((ext_vector_type(4)));
typedef unsigned short u16x4 __attribute__((ext_vector_type(4)));

__device__ __forceinline__ float bflo(uint32_t u) {
    union { uint32_t u; float f; } c; c.u = u << 16; return c.f;
}
__device__ __forceinline__ float bfhi(uint32_t u) {
    union { uint32_t u; float f; } c; c.u = u & 0xffff0000u; return c.f;
}

// ---- fused fp32 -> bf16 convert of BOTH tables in one launch ----
__global__ __launch_bounds__(256) void convert_tables_kernel(
    const f32x4* __restrict__ wsrc, u16x4* __restrict__ wdst, int wn4,
    const f32x4* __restrict__ vsrc, u16x4* __restrict__ vdst, int vn4)
{
    int i = blockIdx.x * blockDim.x + threadIdx.x;
    const f32x4* src; u16x4* dst; int j;
    if (i < wn4) { src = wsrc; dst = wdst; j = i; }
    else         { src = vsrc; dst = vdst; j = i - wn4; if (j >= vn4) return; }
    f32x4 v = src[j];
    u16x4 r;
    r.x = __bfloat16_as_ushort(__float2bfloat16(v.x));
    r.y = __bfloat16_as_ushort(__float2bfloat16(v.y));
    r.z = __bfloat16_as_ushort(__float2bfloat16(v.z));
    r.w = __bfloat16_as_ushort(__float2bfloat16(v.w));
    dst[j] = r;
}

// ---- main: thread-per-output, bf16 W and V, nt store on out ----
__global__ __launch_bounds__(256) void edge_linear_bf16wv_kernel(
    const uint32_t* __restrict__ vbf,        // bf16[NUM_VALUES][8] as uint32[.][4]
    const uint32_t* __restrict__ wbf,        // bf16[NUM_W][8][8]  as uint32[.][32]
    const int*      __restrict__ input_idx,  // [E]
    const int*      __restrict__ weight_idx, // [E]
    float*          __restrict__ out,        // fp32[E][8]
    int E)
{
    int gid = blockIdx.x * blockDim.x + threadIdx.x;
    int e = gid >> 3;
    if (e >= E) return;
    int o = gid & 7;

    int iidx = input_idx[e];
    int widx = weight_idx[e];

    const u32x4* xp = (const u32x4*)(vbf + (size_t)iidx * 4u);
    const u32x4* wp = (const u32x4*)(wbf + (size_t)widx * 32u + (uint32_t)o * 4u);

    u32x4 wv = *wp;        // 8 bf16 of W row o (one 16 B load, cached)
    u32x4 xv = *xp;        // 8 bf16 of x      (one 16 B load, cached)

    float acc = 0.0f;
    acc = fmaf(bflo(wv.x), bflo(xv.x), acc);
    acc = fmaf(bfhi(wv.x), bfhi(xv.x), acc);
    acc = fmaf(bflo(wv.y), bflo(xv.y), acc);
    acc = fmaf(bfhi(wv.y), bfhi(xv.y), acc);
    acc = fmaf(bflo(wv.z), bflo(xv.z), acc);
    acc = fmaf(bfhi(wv.z), bfhi(xv.z), acc);
    acc = fmaf(bflo(wv.w), bflo(xv.w), acc);
    acc = fmaf(bfhi(wv.w), bfhi(xv.w), acc);

    __builtin_nontemporal_store(acc, &out[gid]);   // zero-reuse: don't allocate
}

// ---- round-0 path: bf16 weights only (if ws fits just the W table) ----
__global__ __launch_bounds__(256) void edge_linear_bf16w_kernel(
    const float*    __restrict__ values,
    const uint32_t* __restrict__ wbf,
    const int*      __restrict__ input_idx,
    const int*      __restrict__ weight_idx,
    float*          __restrict__ out,
    int E)
{
    int gid = blockIdx.x * blockDim.x + threadIdx.x;
    int e = gid >> 3;
    if (e >= E) return;
    int o = gid & 7;
    int iidx = input_idx[e];
    int widx = weight_idx[e];
    const f32x4* xp = (const f32x4*)(values + (size_t)iidx * 8u);
    const u32x4* wp = (const u32x4*)(wbf + (size_t)widx * 32u + (uint32_t)o * 4u);
    u32x4 wv = *wp;
    f32x4 x0 = xp[0];
    f32x4 x1 = xp[1];
    float acc = 0.0f;
    acc = fmaf(bflo(wv.x), x0.x, acc);
    acc = fmaf(bfhi(wv.x), x0.y, acc);
    acc = fmaf(bflo(wv.y), x0.z, acc);
    acc = fmaf(bfhi(wv.y), x0.w, acc);
    acc = fmaf(bflo(wv.z), x1.x, acc);
    acc = fmaf(bfhi(wv.z), x1.y, acc);
    acc = fmaf(bflo(wv.w), x1.z, acc);
    acc = fmaf(bfhi(wv.w), x1.w, acc);
    __builtin_nontemporal_store(acc, &out[gid]);
}

// ---- f32 fallback ----
__global__ __launch_bounds__(256) void edge_linear_f32_kernel(
    const float* __restrict__ values,
    const float* __restrict__ weights,
    const int*   __restrict__ input_idx,
    const int*   __restrict__ weight_idx,
    float*       __restrict__ out,
    int E)
{
    int gid = blockIdx.x * blockDim.x + threadIdx.x;
    int e = gid >> 3;
    if (e >= E) return;
    int o = gid & 7;
    int iidx = input_idx[e];
    int widx = weight_idx[e];
    const float4* xp = (const float4*)(values  + (size_t)iidx * 8u);
    const float4* wp = (const float4*)(weights + (size_t)widx * 64u + (uint32_t)o * 8u);
    float4 x0 = xp[0], x1 = xp[1], w0 = wp[0], w1 = wp[1];
    float acc = 0.0f;
    acc = fmaf(w0.x, x0.x, acc); acc = fmaf(w0.y, x0.y, acc);
    acc = fmaf(w0.z, x0.z, acc); acc = fmaf(w0.w, x0.w, acc);
    acc = fmaf(w1.x, x1.x, acc); acc = fmaf(w1.y, x1.y, acc);
    acc = fmaf(w1.z, x1.z, acc); acc = fmaf(w1.w, x1.w, acc);
    out[gid] = acc;
}

extern "C" void kernel_launch(void* const* d_in, const int* in_sizes, int n_in,
                              void* d_out, int out_size, void* d_ws, size_t ws_size,
                              hipStream_t stream) {
    const float* values     = (const float*)d_in[0];
    const float* weights    = (const float*)d_in[1];
    const int*   input_idx  = (const int*)d_in[2];
    const int*   weight_idx = (const int*)d_in[3];
    float*       out        = (float*)d_out;

    int NV = in_sizes[0];               // floats in value table (8.4M)
    int NW = in_sizes[1];               // floats in weight table (4.19M)
    int E  = in_sizes[2];               // 4194304 edges

    size_t need_w  = (size_t)NW * sizeof(uint16_t);          // 8.4 MB
    size_t v_off   = (need_w + 255u) & ~(size_t)255u;        // align values table
    size_t need_wv = v_off + (size_t)NV * sizeof(uint16_t);  // + 16.8 MB

    long long threads = (long long)E * 8;
    int block = 256;
    int grid = (int)((threads + block - 1) / block);

    if (ws_size >= need_wv) {
        uint16_t* wbf = (uint16_t*)d_ws;
        uint16_t* vbf = (uint16_t*)((char*)d_ws + v_off);
        int wn4 = NW / 4;
        int vn4 = NV / 4;
        int tn4 = wn4 + vn4;
        convert_tables_kernel<<<(tn4 + 255) / 256, 256, 0, stream>>>(
            (const f32x4*)weights, (u16x4*)wbf, wn4,
            (const f32x4*)values,  (u16x4*)vbf, vn4);
        edge_linear_bf16wv_kernel<<<grid, block, 0, stream>>>(
            (const uint32_t*)vbf, (const uint32_t*)wbf,
            input_idx, weight_idx, out, E);
    } else if (ws_size >= need_w) {
        int wn4 = NW / 4;
        convert_tables_kernel<<<(wn4 + 255) / 256, 256, 0, stream>>>(
            (const f32x4*)weights, (u16x4*)d_ws, wn4,
            (const f32x4*)weights, (u16x4*)d_ws, 0);
        edge_linear_bf16w_kernel<<<grid, block, 0, stream>>>(
            values, (const uint32_t*)d_ws, input_idx, weight_idx, out, E);
    } else {
        edge_linear_f32_kernel<<<grid, block, 0, stream>>>(
            values, weights, input_idx, weight_idx, out, E);
    }
}